// Round 16
// baseline (87.969 us; speedup 1.0000x reference)
//
#include <hip/hip_runtime.h>

// Problem constants (B=2, T=2048, D=1024, N_EXP=8, TOP_K=2, CAP_FACTOR=1.25)
#define N_TOK   4096
#define DDIM    1024
#define N_EXP   8
#define CAP     1280                       // floor(2*1.25*4096/8), even, >=4
#define ROW     (N_EXP * CAP)              // 10240 floats per token row
#define CB_ELEMS (N_TOK * ROW)             // 41,943,040 floats per output tensor

typedef __attribute__((ext_vector_type(4))) float f32x4;

// ws layout:
//   [0,     8192)  : u8   eb[8192]   expert id per k-major entry i=k*4096+t
//   [8192,  24576) : f32  p0[4096]   softmax weight, slot k=0
//   [24576, 40960) : f32  p1[4096]   softmax weight, slot k=1

// ---------------------------------------------------------------------------
// Kernel 1: FUSED router + zero-fill. One block per token (4096 blocks):
//   - GEMV loads issued FIRST (1 x-float4 + 8 wg-float4 per lane; vmcnt is an
//     in-order FIFO, so waiting for these does NOT drain the younger stores),
//   - then the 80 KB zero-store stream for chunk t (R9-proven addressing),
//   - then the 8-expert dot + top-2 + softmax, hidden under the store drain.
// Every block has the identical profile -> no R4-style role imbalance.
// ---------------------------------------------------------------------------
__global__ __launch_bounds__(256) void router_zero_kernel(
    const float* __restrict__ x, const float* __restrict__ wg,
    unsigned char* __restrict__ eb,
    float* __restrict__ p0, float* __restrict__ p1,
    float* __restrict__ out)
{
    __shared__ float part[4][N_EXP];
    const int t    = blockIdx.x;
    const int wave = threadIdx.x >> 6;
    const int lane = threadIdx.x & 63;
    const int d4   = wave * 64 + lane;               // 0..255 float4 index

    // ---- GEMV loads first (oldest in the vmcnt FIFO) -----------------------
    const float4 xv = ((const float4*)(x + (size_t)t * DDIM))[d4];
    float4 wv[N_EXP];
#pragma unroll
    for (int e = 0; e < N_EXP; ++e)
        wv[e] = ((const float4*)wg)[e * 256 + d4];   // 32 KB, L2-hot

    // ---- zero-store stream: chunk t = [8 + t*20480, 8 + (t+1)*20480) -------
    f32x4* b4 = (f32x4*)(out + 8 + (size_t)t * (2 * ROW));   // 5120 f32x4
    const f32x4 z = {0.f, 0.f, 0.f, 0.f};
#pragma unroll
    for (int it = 0; it < 20; ++it)
        b4[threadIdx.x + it * 256] = z;

    // ---- dot products (waitcnt here only drains the 9 loads) ---------------
    float acc[N_EXP];
#pragma unroll
    for (int e = 0; e < N_EXP; ++e) {
        acc[e] = fmaf(xv.x, wv[e].x,
                 fmaf(xv.y, wv[e].y,
                 fmaf(xv.z, wv[e].z, xv.w * wv[e].w)));
#pragma unroll
        for (int off = 32; off >= 1; off >>= 1)
            acc[e] += __shfl_xor(acc[e], off, 64);
    }
    if (lane == 0) {
#pragma unroll
        for (int e = 0; e < N_EXP; ++e) part[wave][e] = acc[e];
    }
    __syncthreads();

    if (threadIdx.x == 0) {
        // stable top-2 (strict >) matches jax.lax.top_k tie-breaking
        float v0 = -3.402823466e38f, v1 = -3.402823466e38f;
        int   i0 = 0, i1 = 0;
#pragma unroll
        for (int e = 0; e < N_EXP; ++e) {
            const float v = part[0][e] + part[1][e] + part[2][e] + part[3][e];
            if (v > v0)      { v1 = v0; i1 = i0; v0 = v; i0 = e; }
            else if (v > v1) { v1 = v;  i1 = e; }
        }
        const float ex  = expf(v1 - v0);
        const float inv = 1.f / (1.f + ex);
        p0[t] = inv;                    // softmax([v0,v1])[0]
        p1[t] = ex * inv;               // softmax([v0,v1])[1]
        eb[t]         = (unsigned char)i0;   // byte stores: no cross-block race
        eb[N_TOK + t] = (unsigned char)i1;
    }
}

// ---------------------------------------------------------------------------
// Kernel 2: fixup — 2048 blocks x 4 waves; wave w of block j owns k-major
// entry i = 4j + w. Rank = # prior same-expert entries, counted from the
// LDS-staged 8 KB byte array. <=2 scattered stores per entry (cb + mask).
// Block 0 adds used_capacity. Runs after K1 -> kernel-boundary ordering.
// ---------------------------------------------------------------------------
__global__ __launch_bounds__(256) void fixup_kernel(
    const unsigned int* __restrict__ eb32, const float* __restrict__ p0,
    const float* __restrict__ p1, float* __restrict__ out)
{
    __shared__ unsigned int spk[2048];   // 8 KB: 8192 expert bytes
#pragma unroll
    for (int j = 0; j < 8; ++j)
        spk[threadIdx.x + j * 256] = eb32[threadIdx.x + j * 256];
    __syncthreads();

    const int wave = threadIdx.x >> 6;
    const int lane = threadIdx.x & 63;
    const int i    = blockIdx.x * 4 + wave;          // k-major entry, < 8192
    const int t    = i & (N_TOK - 1);
    const int k    = i >> 12;

    unsigned int w[32];
#pragma unroll
    for (int j = 0; j < 32; ++j) w[j] = spk[lane + j * 64];  // all 2048 words

    const int e = (int)((spk[i >> 2] >> ((i & 3) * 8)) & 0xFF);
    int cnt = 0;
#pragma unroll
    for (int j = 0; j < 32; ++j) {
        const int bi = (lane + j * 64) * 4;          // entry idx of byte 0
#pragma unroll
        for (int s = 0; s < 4; ++s)
            cnt += (bi + s < i && (int)((w[j] >> (8 * s)) & 0xFF) == e) ? 1 : 0;
    }
#pragma unroll
    for (int off = 32; off >= 1; off >>= 1)
        cnt += __shfl_xor(cnt, off, 64);

    if (lane == 0 && cnt < CAP) {                    // dropped tokens skipped
        const float wv = k ? p1[t] : p0[t];
        float* cb = out + 8 + (size_t)t * ROW + (size_t)e * CAP + cnt;
        cb[0]        = wv;
        cb[CB_ELEMS] = (wv != 0.f) ? 1.f : 0.f;
    }

    // block 0: used_capacity[8] — wave handles experts 2*wave, 2*wave+1
    if (blockIdx.x == 0) {
#pragma unroll
        for (int q = 0; q < 2; ++q) {
            const int ee = wave * 2 + q;
            int c = 0;
#pragma unroll
            for (int j = 0; j < 32; ++j) {
#pragma unroll
                for (int s = 0; s < 4; ++s)
                    c += ((int)((w[j] >> (8 * s)) & 0xFF) == ee) ? 1 : 0;
            }
#pragma unroll
            for (int off = 32; off >= 1; off >>= 1)
                c += __shfl_xor(c, off, 64);
            if (lane == 0) out[ee] = (float)min(c, CAP);
        }
    }
}

// ---------------------------------------------------------------------------
extern "C" void kernel_launch(void* const* d_in, const int* in_sizes, int n_in,
                              void* d_out, int out_size, void* d_ws, size_t ws_size,
                              hipStream_t stream)
{
    const float* x  = (const float*)d_in[0];   // [2,2048,1024] f32
    const float* wg = (const float*)d_in[1];   // [8,1024] f32
    float* out = (float*)d_out;                // [8] used | cb | mask

    char*          ws = (char*)d_ws;
    unsigned char* eb = (unsigned char*)(ws);
    float*         p0 = (float*)(ws + 8192);
    float*         p1 = (float*)(ws + 24576);

    router_zero_kernel<<<N_TOK, 256, 0, stream>>>(x, wg, eb, p0, p1, out);
    fixup_kernel<<<2048, 256, 0, stream>>>((const unsigned int*)eb, p0, p1, out);
}

// Round 17
// 75.845 us; speedup vs baseline: 1.1599x; 1.1599x over previous
//
#include <hip/hip_runtime.h>

// Problem constants (B=2, T=2048, D=1024, N_EXP=8, TOP_K=2, CAP_FACTOR=1.25)
#define N_TOK   4096
#define DDIM    1024
#define N_EXP   8
#define CAP     1280                       // floor(2*1.25*4096/8), even, >=4
#define ROW     (N_EXP * CAP)              // 10240 floats per token row
#define CB_ELEMS (N_TOK * ROW)             // 41,943,040 floats per output tensor

typedef __attribute__((ext_vector_type(4))) float f32x4;

// ws layout:
//   [0,     4096)  : uint  pk[1024]   packed 4-bit expert ids, entry-major:
//                    entry i = k*4096 + t -> nibble (i&7) of word (i>>3)
//   [4096,  20480) : f32   p0[4096]   softmax weight, slot k=0
//   [20480, 36864) : f32   p1[4096]   softmax weight, slot k=1

// ---------------------------------------------------------------------------
// Kernel 1: router — 4096x8 GEMV, top-2, softmax over the 2 selected logits.
// One wave per token (4/block). Each block non-atomically stores its 4 tokens'
// expert nibbles as two 16-bit halfwords (disjoint across blocks). (R9-proven)
// ---------------------------------------------------------------------------
__global__ __launch_bounds__(256) void router_kernel(
    const float* __restrict__ x, const float* __restrict__ wg,
    unsigned int* __restrict__ pk,
    float* __restrict__ p0, float* __restrict__ p1)
{
    __shared__ int se0[4], se1[4];
    const int wave = threadIdx.x >> 6;
    const int lane = threadIdx.x & 63;
    const int t = blockIdx.x * 4 + wave;

    const float4* xt  = (const float4*)(x + (size_t)t * DDIM);  // 256 float4
    const float4* wg4 = (const float4*)wg;                      // [8][256]

    float acc[N_EXP];
#pragma unroll
    for (int e = 0; e < N_EXP; ++e) acc[e] = 0.f;

#pragma unroll
    for (int it = 0; it < 4; ++it) {
        const int d4 = lane + it * 64;
        const float4 xv = xt[d4];
#pragma unroll
        for (int e = 0; e < N_EXP; ++e) {
            const float4 wv = wg4[e * 256 + d4];
            acc[e] = fmaf(xv.x, wv.x,
                     fmaf(xv.y, wv.y,
                     fmaf(xv.z, wv.z,
                     fmaf(xv.w, wv.w, acc[e]))));
        }
    }

#pragma unroll
    for (int e = 0; e < N_EXP; ++e) {
#pragma unroll
        for (int off = 32; off >= 1; off >>= 1)
            acc[e] += __shfl_xor(acc[e], off, 64);
    }

    if (lane == 0) {
        // stable top-2 (strict >) matches jax.lax.top_k tie-breaking
        float v0 = -3.402823466e38f, v1 = -3.402823466e38f;
        int   i0 = 0, i1 = 0;
#pragma unroll
        for (int e = 0; e < N_EXP; ++e) {
            const float v = acc[e];
            if (v > v0)      { v1 = v0; i1 = i0; v0 = v; i0 = e; }
            else if (v > v1) { v1 = v;  i1 = e; }
        }
        const float ex  = expf(v1 - v0);
        const float inv = 1.f / (1.f + ex);
        p0[t] = inv;        // softmax([v0,v1])[0]
        p1[t] = ex * inv;   // softmax([v0,v1])[1]
        se0[wave] = i0;
        se1[wave] = i1;
    }
    __syncthreads();

    if (threadIdx.x == 0) {
        const int b = blockIdx.x;
        unsigned short* pks = (unsigned short*)pk;
        const unsigned short h0 = (unsigned short)(se0[0] | (se0[1] << 4) |
                                                   (se0[2] << 8) | (se0[3] << 12));
        const unsigned short h1 = (unsigned short)(se1[0] | (se1[1] << 4) |
                                                   (se1[2] << 8) | (se1[3] << 12));
        pks[b]        = h0;   // k=0 entries 4b..4b+3
        pks[1024 + b] = h1;   // k=1 entries 4096+4b..4096+4b+3
    }
}

// ---------------------------------------------------------------------------
// Kernel 2: fill — one contiguous 80 KB chunk per block (R9 champion, 75.8us).
// Zero stores issued first; 4 KB pk staged to LDS; each wave recomputes the
// exact k-major prefix rank for its (token, slot) entry by nibble-counting,
// overlapped with the store drain; one barrier; <=4 L2-warm fixups.
// Blocks [0,2048): cb rows of token pair; [2048,4096): mask rows.
// Block 0 also emits used_capacity.
// ---------------------------------------------------------------------------
__global__ __launch_bounds__(256) void fill_kernel(
    const unsigned int* __restrict__ pk, const float* __restrict__ p0,
    const float* __restrict__ p1, float* __restrict__ out)
{
    __shared__ unsigned int spk[1024];   // 4 KB packed expert ids
    __shared__ int s_e[4], s_r[4];

    const int  b     = blockIdx.x;
    const bool is_cb = (b < 2048);
    const int  t0    = (is_cb ? b : (b - 2048)) * 2;   // token pair base

    float* base = out + 8 + (is_cb ? 0 : (size_t)CB_ELEMS) + (size_t)t0 * ROW;
    f32x4* b4   = (f32x4*)base;                  // 5120 f32x4 = 80 KB contiguous
    const f32x4 z = {0.f, 0.f, 0.f, 0.f};

    // issue the zero stores first; they drain while we scan
#pragma unroll
    for (int it = 0; it < 20; ++it)
        b4[threadIdx.x + it * 256] = z;

#pragma unroll
    for (int j = 0; j < 4; ++j)
        spk[threadIdx.x + j * 256] = pk[threadIdx.x + j * 256];
    __syncthreads();                             // spk visible (stores also drained)

    const int wave = threadIdx.x >> 6;
    const int lane = threadIdx.x & 63;

    // wave w -> entry (token t0+(w>>1), slot w&1); rank = # prior same-e entries
    const int tt = t0 + (wave >> 1);
    const int i  = (wave & 1) * N_TOK + tt;
    const int e  = (spk[i >> 3] >> ((i & 7) * 4)) & 0xF;

    int cnt = 0;
    for (int j = 0; j < 16; ++j) {
        const unsigned int w  = spk[lane + j * 64];   // stride-64: 2-way bank, free
        const int          bi = (lane + j * 64) * 8;  // entry index of nibble 0
#pragma unroll
        for (int s = 0; s < 8; ++s)
            cnt += (bi + s < i && (int)((w >> (4 * s)) & 0xF) == e) ? 1 : 0;
    }
#pragma unroll
    for (int off = 32; off >= 1; off >>= 1)
        cnt += __shfl_xor(cnt, off, 64);

    if (lane == 0) { s_e[wave] = e; s_r[wave] = cnt; }
    __syncthreads();                             // vmcnt(0): zeros done; ranks visible

    if (threadIdx.x < 4) {
        const int r = s_r[threadIdx.x];
        if (r < CAP) {                           // dropped tokens (rank>=cap) skipped
            const int   tt2 = t0 + (threadIdx.x >> 1);
            const float w   = (threadIdx.x & 1) ? p1[tt2] : p0[tt2];
            const float v   = is_cb ? w : ((w != 0.f) ? 1.f : 0.f);
            base[(size_t)(tt2 - t0) * ROW + s_e[threadIdx.x] * CAP + r] = v;
        }
    }

    // block 0: used_capacity[8] = min(total per expert, CAP)
    if (b == 0) {
        for (int ee = wave * 2; ee < wave * 2 + 2; ++ee) {
            int c = 0;
            for (int j = 0; j < 16; ++j) {
                const unsigned int w = spk[lane + j * 64];
#pragma unroll
                for (int s = 0; s < 8; ++s)
                    c += ((int)((w >> (4 * s)) & 0xF) == ee) ? 1 : 0;
            }
#pragma unroll
            for (int off = 32; off >= 1; off >>= 1)
                c += __shfl_xor(c, off, 64);
            if (lane == 0) out[ee] = (float)min(c, CAP);
        }
    }
}

// ---------------------------------------------------------------------------
extern "C" void kernel_launch(void* const* d_in, const int* in_sizes, int n_in,
                              void* d_out, int out_size, void* d_ws, size_t ws_size,
                              hipStream_t stream)
{
    const float* x  = (const float*)d_in[0];   // [2,2048,1024] f32
    const float* wg = (const float*)d_in[1];   // [8,1024] f32
    float* out = (float*)d_out;                // [8] used | cb | mask

    char*         ws = (char*)d_ws;
    unsigned int* pk = (unsigned int*)(ws);
    float*        p0 = (float*)(ws + 4096);
    float*        p1 = (float*)(ws + 20480);

    router_kernel<<<N_TOK / 4, 256, 0, stream>>>(x, wg, pk, p0, p1);
    fill_kernel<<<4096, 256, 0, stream>>>(pk, p0, p1, out);
}